// Round 5
// baseline (761.058 us; speedup 1.0000x reference)
//
#include <hip/hip_runtime.h>
#include <hip/hip_fp16.h>
#include <math.h>

#define B_    128
#define NTOK  577
#define KSEL  172
#define M_WG  (B_*NTOK)    // 73856
#define M_SEL (B_*KSEL)    // 22016
#define DELTA 8e-3f        // uncertainty half-band; f16-score err sigma ~3e-4 => 13 sigma

typedef float f32x4 __attribute__((ext_vector_type(4)));
typedef short s16x8 __attribute__((ext_vector_type(8)));
typedef short s16x4 __attribute__((ext_vector_type(4)));
typedef _Float16 f16x8 __attribute__((ext_vector_type(8)));

// async global->LDS 16B: per-lane global src, lane-contiguous LDS dest
__device__ __forceinline__ void gll16(const void* g, void* l) {
    __builtin_amdgcn_global_load_lds(
        (const __attribute__((address_space(1))) unsigned int*)g,
        (__attribute__((address_space(3))) unsigned int*)l, 16, 0, 0);
}

// ---------------- zero init (scores + bn stats) ----------------
__global__ void zero_kernel(float* __restrict__ w, float* __restrict__ stats) {
    int i = blockIdx.x * 256 + threadIdx.x;
    if (i < M_WG) w[i] = 0.f;
    if (i < 1024) stats[i] = 0.f;
}

// ------- weight transpose -> f16, k-contiguous rows (all four weights) -------
__global__ __launch_bounds__(256) void transpose_f16_kernel(
    const float* __restrict__ wgw1, const float* __restrict__ mw0,
    const float* __restrict__ mw1, const float* __restrict__ fcw,
    short* __restrict__ w1t, short* __restrict__ w0t,
    short* __restrict__ mw1t, short* __restrict__ fct)
{
    const int z = blockIdx.z;
    const float* src; short* dst; int N;
    if (z == 0)      { src = wgw1; dst = w1t;  N = 512;  }
    else if (z == 1) { src = mw0;  dst = w0t;  N = 512;  }
    else if (z == 2) { src = mw1;  dst = mw1t; N = 1024; }
    else             { src = fcw;  dst = fct;  N = 1024; }
    const int n0 = blockIdx.x * 64;
    if (n0 >= N) return;
    const int k0 = blockIdx.y * 64;
    __shared__ float t[64][65];
    const int tid = threadIdx.x;
#pragma unroll
    for (int rr = 0; rr < 16; rr++) {
        int kl = rr * 4 + (tid >> 6), nl = tid & 63;
        t[kl][nl] = src[(size_t)(k0 + kl) * N + n0 + nl];
    }
    __syncthreads();
    const int nl = tid >> 2, kc = tid & 3;
    short hs[16];
#pragma unroll
    for (int j = 0; j < 16; j++)
        hs[j] = (short)__half_as_ushort(__float2half(t[kc * 16 + j][nl]));
    size_t o = (size_t)(n0 + nl) * 512 + k0 + kc * 16;
    *(s16x8*)(dst + o)     = *(s16x8*)hs;
    *(s16x8*)(dst + o + 8) = *(s16x8*)(hs + 8);
}

// -------- wg approx scores (f16 single-pass, 128x256 tile, double-buffered) ---
// s~[token] = sum_n relu((F@W1)[n] + b1[n]) * v[n]
__global__ __launch_bounds__(256) void wg_f16_kernel(
    const float* __restrict__ F, const short* __restrict__ W1t,
    const float* __restrict__ b1, const float* __restrict__ v,
    float* __restrict__ w_out)
{
    __shared__ short A2[2][4096];   // [kqs][row(128)][8] f16
    __shared__ short B2[2][8192];   // [kqs][col(256)][8] f16
    const int tid = threadIdx.x, lane = tid & 63, wn = tid >> 6;
    const int r = lane & 15, kq = lane >> 4;
    const int rowbase = blockIdx.y * 128, nbase = blockIdx.x * 256;
    float av[2][8];

    // prologue: stage k-step 0 into buffer 0
    {
        int k0 = 0;
#pragma unroll
        for (int p = 0; p < 4; p++) {
            int c = tid + p * 256, col = c & 255, kqs = c >> 8;
            gll16(W1t + (size_t)(nbase + col) * 512 + k0 + kqs * 8, &B2[0][c * 8]);
        }
#pragma unroll
        for (int p = 0; p < 2; p++) {
            int c = tid + p * 256, row = c & 127, kqs = c >> 7;
            const float* s = F + (size_t)(rowbase + row) * 512 + k0 + kqs * 8;
            f32x4 u0 = *(const f32x4*)s, u1 = *(const f32x4*)(s + 4);
#pragma unroll
            for (int j = 0; j < 4; j++) { av[p][j] = u0[j]; av[p][4 + j] = u1[j]; }
            short hs[8];
#pragma unroll
            for (int j = 0; j < 8; j++) hs[j] = (short)__half_as_ushort(__float2half(av[p][j]));
            *(s16x8*)&A2[0][kqs * 1024 + row * 8] = *(s16x8*)hs;
        }
    }
    __syncthreads();

    f32x4 acc[8][4];
#pragma unroll
    for (int i = 0; i < 8; i++)
#pragma unroll
        for (int j = 0; j < 4; j++) acc[i][j] = (f32x4)(0.0f);

    for (int km = 0; km < 16; km++) {
        const int pb = km & 1;
        if (km < 15) {
            int k0 = (km + 1) * 32;
#pragma unroll
            for (int p = 0; p < 4; p++) {
                int c = tid + p * 256, col = c & 255, kqs = c >> 8;
                gll16(W1t + (size_t)(nbase + col) * 512 + k0 + kqs * 8, &B2[pb ^ 1][c * 8]);
            }
#pragma unroll
            for (int p = 0; p < 2; p++) {
                int c = tid + p * 256, row = c & 127, kqs = c >> 7;
                const float* s = F + (size_t)(rowbase + row) * 512 + k0 + kqs * 8;
                f32x4 u0 = *(const f32x4*)s, u1 = *(const f32x4*)(s + 4);
#pragma unroll
                for (int j = 0; j < 4; j++) { av[p][j] = u0[j]; av[p][4 + j] = u1[j]; }
            }
        }
        f16x8 bfrag[4];
#pragma unroll
        for (int nf = 0; nf < 4; nf++)
            bfrag[nf] = *(const f16x8*)&B2[pb][kq * 2048 + (wn * 64 + nf * 16 + r) * 8];
#pragma unroll
        for (int mf = 0; mf < 8; mf++) {
            f16x8 a = *(const f16x8*)&A2[pb][kq * 1024 + (mf * 16 + r) * 8];
#pragma unroll
            for (int nf = 0; nf < 4; nf++)
                acc[mf][nf] = __builtin_amdgcn_mfma_f32_16x16x32_f16(a, bfrag[nf], acc[mf][nf], 0, 0, 0);
        }
        if (km < 15) {
#pragma unroll
            for (int p = 0; p < 2; p++) {
                int c = tid + p * 256, row = c & 127, kqs = c >> 7;
                short hs[8];
#pragma unroll
                for (int j = 0; j < 8; j++) hs[j] = (short)__half_as_ushort(__float2half(av[p][j]));
                *(s16x8*)&A2[pb ^ 1][kqs * 1024 + row * 8] = *(s16x8*)hs;
            }
        }
        __syncthreads();
    }

    float b1v[4], vv[4];
#pragma unroll
    for (int nf = 0; nf < 4; nf++) {
        int col = nbase + wn * 64 + nf * 16 + r;
        b1v[nf] = b1[col]; vv[nf] = v[col];
    }
#pragma unroll
    for (int mf = 0; mf < 8; mf++)
#pragma unroll
        for (int i = 0; i < 4; i++) {
            float s = 0.f;
#pragma unroll
            for (int nf = 0; nf < 4; nf++)
                s += fmaxf(acc[mf][nf][i] + b1v[nf], 0.f) * vv[nf];
            s += __shfl_xor(s, 1); s += __shfl_xor(s, 2);
            s += __shfl_xor(s, 4); s += __shfl_xor(s, 8);
            if (r == 0)
                atomicAdd(&w_out[rowbase + mf * 16 + kq * 4 + i], s);
        }
}

// ------- topk on approx scores + certain/uncertain classification -------------
// Correctness: if every |s~ - s| <= DELTA/2 then {s~ > t~+DELTA} are all truly
// in top-172 and {s~ < t~-DELTA} truly out; the boundary is decided among the
// uncertain band by exact scores (refine kernel). Set selection only — final
// indices are sorted ascending, so intra-set order never matters.
__global__ __launch_bounds__(512) void topk2_kernel(
    const float* __restrict__ w, int* __restrict__ cin, int* __restrict__ unc,
    int* __restrict__ meta)
{
    __shared__ float sval[1024];
    __shared__ int   sidx[1024];
    __shared__ int mcnt, ucnt;
    __shared__ float thr_s;
    const int b = blockIdx.x;
    const int tid = threadIdx.x;
    for (int i = tid; i < 1024; i += 512) {
        if (i < 576) { sval[i] = w[b * NTOK + 1 + i]; sidx[i] = 1 + i; }
        else         { sval[i] = -1e38f;              sidx[i] = 0x7fffffff; }
    }
    __syncthreads();
    for (int ksz = 2; ksz <= 1024; ksz <<= 1) {
        for (int j = ksz >> 1; j > 0; j >>= 1) {
            int i = ((tid & ~(j - 1)) << 1) | (tid & (j - 1));
            int ixj = i | j;
            float va = sval[i], vb = sval[ixj];
            int ia = sidx[i], ib = sidx[ixj];
            bool a_first = (va > vb) || (va == vb && ia < ib);
            bool dirDesc = ((i & ksz) == 0);
            bool doswap = dirDesc ? (!a_first) : a_first;
            if (doswap) { sval[i] = vb; sval[ixj] = va; sidx[i] = ib; sidx[ixj] = ia; }
            __syncthreads();
        }
    }
    if (tid == 0) { thr_s = sval[KSEL - 1]; mcnt = 0; ucnt = 0; }
    __syncthreads();
    const float thr = thr_s;
    for (int i = tid; i < 576; i += 512) {
        float vv = sval[i]; int id = sidx[i];
        if (vv > thr + DELTA) {
            int p = atomicAdd(&mcnt, 1);
            cin[b * KSEL + p] = id;
        } else if (vv >= thr - DELTA) {
            int p = atomicAdd(&ucnt, 1);
            if (p < 256) unc[b * 256 + p] = id;
        }
    }
    __syncthreads();
    if (tid == 0) {
        int m = mcnt;                      // <= 171 (rank-171 token is in band)
        int u = (ucnt < 256) ? ucnt : 256; // E[u]~5; overflow statistically nil
        meta[b * 4]     = m;
        meta[b * 4 + 1] = KSEL - m;        // r slots to fill from uncertain
        meta[b * 4 + 2] = u;
    }
}

// -------- exact fp32 re-score of uncertain tokens (tiny: ~5 tokens/batch) -----
__global__ __launch_bounds__(256) void refine_kernel(
    const float* __restrict__ F, const float* __restrict__ W1,
    const float* __restrict__ b1, const float* __restrict__ v,
    const int* __restrict__ unc, const int* __restrict__ meta,
    float* __restrict__ rscore)
{
    const int b = blockIdx.y, tid = threadIdx.x;
    const int u = meta[b * 4 + 2];
    __shared__ float fr[512];
    __shared__ float redbuf[4];
    for (int s = blockIdx.x; s < u; s += 32) {
        int tok = unc[b * 256 + s];
        __syncthreads();
        fr[tid]       = F[((size_t)b * NTOK + tok) * 512 + tid];
        fr[tid + 256] = F[((size_t)b * NTOK + tok) * 512 + tid + 256];
        __syncthreads();
        float a0 = b1[tid], a1 = b1[tid + 256];
#pragma unroll 4
        for (int k = 0; k < 512; k++) {
            float fk = fr[k];
            a0 = fmaf(fk, W1[(size_t)k * 512 + tid], a0);
            a1 = fmaf(fk, W1[(size_t)k * 512 + tid + 256], a1);
        }
        float p = fmaxf(a0, 0.f) * v[tid] + fmaxf(a1, 0.f) * v[tid + 256];
#pragma unroll
        for (int off = 32; off > 0; off >>= 1) p += __shfl_down(p, off);
        if ((tid & 63) == 0) redbuf[tid >> 6] = p;
        __syncthreads();
        if (tid == 0) rscore[b * 256 + s] = redbuf[0] + redbuf[1] + redbuf[2] + redbuf[3];
    }
}

// -------- final selection: certain + top-r uncertain (exact), sort ascending --
__global__ __launch_bounds__(256) void select_kernel(
    const int* __restrict__ cin, const int* __restrict__ unc,
    const float* __restrict__ rscore, const int* __restrict__ meta,
    int* __restrict__ idx_out)
{
    const int b = blockIdx.x, tid = threadIdx.x;
    const int m = meta[b * 4], u = meta[b * 4 + 2];
    __shared__ float uval[256];
    __shared__ int   uidx[256];
    __shared__ int   fin[256];
    if (tid < u) { uval[tid] = rscore[b * 256 + tid]; uidx[tid] = unc[b * 256 + tid]; }
    else         { uval[tid] = -1e38f;                uidx[tid] = 0x7fffffff; }
    __syncthreads();
    // bitonic-256 desc by (score, lower idx on tie) — matches jax stable top_k
    for (int ksz = 2; ksz <= 256; ksz <<= 1) {
        for (int j = ksz >> 1; j > 0; j >>= 1) {
            if (tid < 128) {
                int i = ((tid & ~(j - 1)) << 1) | (tid & (j - 1));
                int ixj = i | j;
                float va = uval[i], vb = uval[ixj];
                int ia = uidx[i], ib = uidx[ixj];
                bool a_first = (va > vb) || (va == vb && ia < ib);
                bool dirDesc = ((i & ksz) == 0);
                if (dirDesc ? !a_first : a_first) {
                    uval[i] = vb; uval[ixj] = va; uidx[i] = ib; uidx[ixj] = ia;
                }
            }
            __syncthreads();
        }
    }
    if (tid < m) fin[tid] = cin[b * KSEL + tid];
    else if (tid < KSEL) fin[tid] = uidx[tid - m];   // tid-m < r, top-r uncertain
    else fin[tid] = 0x7fffffff;
    __syncthreads();
    for (int ksz = 2; ksz <= 256; ksz <<= 1) {
        for (int j = ksz >> 1; j > 0; j >>= 1) {
            if (tid < 128) {
                int i = ((tid & ~(j - 1)) << 1) | (tid & (j - 1));
                int ixj = i | j;
                int a = fin[i], bb = fin[ixj];
                bool asc = ((i & ksz) == 0);
                if (asc ? (a > bb) : (a < bb)) { fin[i] = bb; fin[ixj] = a; }
            }
            __syncthreads();
        }
    }
    if (tid < KSEL) idx_out[b * KSEL + tid] = fin[tid];
}

// ---------- gather + l2norm -> f16 (matches reference sel.half()) ----------
__global__ __launch_bounds__(128) void gather_norm_kernel(
    const float* __restrict__ F, const int* __restrict__ idx,
    short* __restrict__ Sh)
{
    const int g = blockIdx.x;
    const int b = g / KSEL;
    const int tok = idx[g];
    const float4* src = (const float4*)(F + ((size_t)b * NTOK + tok) * 512);
    const int t = threadIdx.x;
    float4 v = src[t];
    float ss = v.x * v.x + v.y * v.y + v.z * v.z + v.w * v.w;
#pragma unroll
    for (int off = 32; off > 0; off >>= 1) ss += __shfl_down(ss, off);
    __shared__ float red[2];
    if ((t & 63) == 0) red[t >> 6] = ss;
    __syncthreads();
    float inv = 1.0f / (sqrtf(red[0] + red[1]) + 1e-8f);
    float xs[4] = {v.x * inv, v.y * inv, v.z * inv, v.w * inv};
    short hs[4];
#pragma unroll
    for (int j = 0; j < 4; j++) hs[j] = (short)__half_as_ushort(__float2half(xs[j]));
    *(s16x4*)(Sh + (size_t)g * 512 + t * 4) = *(s16x4*)hs;
}

// -------- x1 = f16(sel @ w0 + b0), fused BN-stat partials (f16 MFMA) --------
__global__ __launch_bounds__(256) void gemm_x1_kernel(
    const short* __restrict__ Sh, const short* __restrict__ W0t,
    const float* __restrict__ b0, short* __restrict__ X1h, float* __restrict__ stats)
{
    __shared__ short A[4096], Bt[8192];
    const int tid = threadIdx.x, lane = tid & 63, wn = tid >> 6;
    const int rowbase = blockIdx.y * 128, nbase = blockIdx.x * 256;
    const int r = lane & 15, kq = lane >> 4;
    f32x4 acc[8][4];
#pragma unroll
    for (int i = 0; i < 8; i++)
#pragma unroll
        for (int j = 0; j < 4; j++) acc[i][j] = (f32x4)(0.0f);
    for (int k0 = 0; k0 < 512; k0 += 32) {
#pragma unroll
        for (int p = 0; p < 2; p++) {
            int c = tid + p * 256, row = c & 127, kqs = c >> 7;
            gll16(Sh + (size_t)(rowbase + row) * 512 + k0 + kqs * 8, A + c * 8);
        }
#pragma unroll
        for (int p = 0; p < 4; p++) {
            int c = tid + p * 256, col = c & 255, kqs = c >> 8;
            gll16(W0t + (size_t)(nbase + col) * 512 + k0 + kqs * 8, Bt + c * 8);
        }
        __syncthreads();
        f16x8 b[4];
#pragma unroll
        for (int nf = 0; nf < 4; nf++)
            b[nf] = *(const f16x8*)(Bt + kq * 2048 + (wn * 64 + nf * 16 + r) * 8);
#pragma unroll
        for (int mf = 0; mf < 8; mf++) {
            f16x8 a = *(const f16x8*)(A + kq * 1024 + (mf * 16 + r) * 8);
#pragma unroll
            for (int nf = 0; nf < 4; nf++)
                acc[mf][nf] = __builtin_amdgcn_mfma_f32_16x16x32_f16(a, b[nf], acc[mf][nf], 0, 0, 0);
        }
        __syncthreads();
    }
#pragma unroll
    for (int nf = 0; nf < 4; nf++) {
        int col = nbase + wn * 64 + nf * 16 + r;
        float b0v = b0[col];
        float cs = 0.f, cq = 0.f;
#pragma unroll
        for (int mf = 0; mf < 8; mf++)
#pragma unroll
            for (int i = 0; i < 4; i++) {
                int row = rowbase + mf * 16 + kq * 4 + i;
                float val = acc[mf][nf][i] + b0v;
                X1h[(size_t)row * 512 + col] = (short)__half_as_ushort(__float2half(val));
                cs += val; cq += val * val;
            }
        cs += __shfl_xor(cs, 16); cs += __shfl_xor(cs, 32);
        cq += __shfl_xor(cq, 16); cq += __shfl_xor(cq, 32);
        if (kq == 0) {
            atomicAdd(&stats[col], cs);
            atomicAdd(&stats[512 + col], cq);
        }
    }
}

__global__ void bn_finalize_kernel(const float* __restrict__ stats,
                                   const float* __restrict__ g,
                                   const float* __restrict__ b,
                                   float* __restrict__ ss)
{
    int c = threadIdx.x;  // 512
    float mean = stats[c] * (1.0f / M_SEL);
    float var = stats[512 + c] * (1.0f / M_SEL) - mean * mean;
    float sc = g[c] * rsqrtf(var + 1e-5f);
    ss[c] = sc;
    ss[512 + c] = b[c] - mean * sc;
}

// ---- out = f16(sel@fc_w + fc_b) + (bnrelu(x1) @ w1 + b1), double-buffered ----
__global__ __launch_bounds__(256) void gemm_out2_kernel(
    const short* __restrict__ Sh, const short* __restrict__ FCt,
    const float* __restrict__ fcb, const short* __restrict__ X1h,
    const short* __restrict__ W1t, const float* __restrict__ ssbuf,
    const float* __restrict__ b1, float* __restrict__ out)
{
    __shared__ short A2[2][4096];
    __shared__ short B2[2][8192];
    __shared__ float sc[512], sh_[512];
    const int tid = threadIdx.x, lane = tid & 63, wn = tid >> 6;
    const int rowbase = blockIdx.y * 128, nbase = blockIdx.x * 256;
    const int r = lane & 15, kq = lane >> 4;
    for (int i = tid; i < 512; i += 256) { sc[i] = ssbuf[i]; sh_[i] = ssbuf[512 + i]; }
    f32x4 acc[8][4];
#pragma unroll
    for (int i = 0; i < 8; i++)
#pragma unroll
        for (int j = 0; j < 4; j++) acc[i][j] = (f32x4)(0.0f);

    // ---- phase A: fc (pure gll16 staging, dbuf) ----
    {
#pragma unroll
        for (int p = 0; p < 2; p++) {
            int c = tid + p * 256, row = c & 127, kqs = c >> 7;
            gll16(Sh + (size_t)(rowbase + row) * 512 + kqs * 8, &A2[0][c * 8]);
        }
#pragma unroll
        for (int p = 0; p < 4; p++) {
            int c = tid + p * 256, col = c & 255, kqs = c >> 8;
            gll16(FCt + (size_t)(nbase + col) * 512 + kqs * 8, &B2[0][c * 8]);
        }
    }
    __syncthreads();
    for (int km = 0; km < 16; km++) {
        const int pb = km & 1;
        if (km < 15) {
            int k0 = (km + 1) * 32;
#pragma unroll
            for (int p = 0; p < 2; p++) {
                int c = tid + p * 256, row = c & 127, kqs = c >> 7;
                gll16(Sh + (size_t)(rowbase + row) * 512 + k0 + kqs * 8, &A2[pb ^ 1][c * 8]);
            }
#pragma unroll
            for (int p = 0; p < 4; p++) {
                int c = tid + p * 256, col = c & 255, kqs = c >> 8;
                gll16(FCt + (size_t)(nbase + col) * 512 + k0 + kqs * 8, &B2[pb ^ 1][c * 8]);
            }
        }
        f16x8 b[4];
#pragma unroll
        for (int nf = 0; nf < 4; nf++)
            b[nf] = *(const f16x8*)&B2[pb][kq * 2048 + (wn * 64 + nf * 16 + r) * 8];
#pragma unroll
        for (int mf = 0; mf < 8; mf++) {
            f16x8 a = *(const f16x8*)&A2[pb][kq * 1024 + (mf * 16 + r) * 8];
#pragma unroll
            for (int nf = 0; nf < 4; nf++)
                acc[mf][nf] = __builtin_amdgcn_mfma_f32_16x16x32_f16(a, b[nf], acc[mf][nf], 0, 0, 0);
        }
        __syncthreads();
    }
    // fc result -> f16 semantics (reference stores feats in fp16)
#pragma unroll
    for (int nf = 0; nf < 4; nf++) {
        float fb = __half2float(__float2half(fcb[nbase + wn * 64 + nf * 16 + r]));
#pragma unroll
        for (int mf = 0; mf < 8; mf++)
#pragma unroll
            for (int i = 0; i < 4; i++) {
                float t = __half2float(__float2half(acc[mf][nf][i]));
                acc[mf][nf][i] = __half2float(__float2half(t + fb));
            }
    }

    // ---- phase B: bnrelu(x1) @ w1 (reg-staged A with BN fused, dbuf) ----
    s16x8 xv[2];
    {
#pragma unroll
        for (int p = 0; p < 2; p++) {
            int c = tid + p * 256, row = c & 127, kqs = c >> 7;
            xv[p] = *(const s16x8*)(X1h + (size_t)(rowbase + row) * 512 + kqs * 8);
        }
#pragma unroll
        for (int p = 0; p < 2; p++) {
            int c = tid + p * 256, row = c & 127, kqs = c >> 7;
            short hs[8];
#pragma unroll
            for (int j = 0; j < 8; j++) {
                float xf = __half2float(__ushort_as_half((unsigned short)xv[p][j]));
                int k = kqs * 8 + j;
                hs[j] = (short)__half_as_ushort(__float2half(fmaxf(fmaf(xf, sc[k], sh_[k]), 0.f)));
            }
            *(s16x8*)&A2[0][kqs * 1024 + row * 8] = *(s16x8*)hs;
        }
#pragma unroll
        for (int p = 0; p < 4; p++) {
            int c = tid + p * 256, col = c & 255, kqs = c >> 8;
            gll16(W1t + (size_t)(nbase + col) * 512 + kqs * 8, &B2[0][c * 8]);
        }
    }
    __syncthreads();
    for (int km = 0; km < 16; km++) {
        const int pb = km & 1;
        if (km < 15) {
            int k0 = (km + 1) * 32;
#pragma unroll
            for (int p = 0; p < 4; p++) {
                int c = tid + p * 256, col = c & 255, kqs = c >> 8;
                gll16(W1t + (size_t)(nbase + col) * 512 + k0 + kqs * 8, &B2[pb ^ 1][c * 8]);
            }
#pragma unroll
            for (int p = 0; p < 2; p++) {
                int c = tid + p * 256, row = c & 127, kqs = c >> 7;
                xv[p] = *(const s16x8*)(X1h + (size_t)(rowbase + row) * 512 + k0 + kqs * 8);
            }
        }
        f16x8 b[4];
#pragma unroll
        for (int nf = 0; nf < 4; nf++)
            b[nf] = *(const f16x8*)&B2[pb][kq * 2048 + (wn * 64 + nf * 16 + r) * 8];
#pragma unroll
        for (int mf = 0; mf < 8; mf++) {
            f16x8 a = *(const f16x8*)&A2[pb][kq * 1024 + (mf * 16 + r) * 8];
#pragma unroll
            for (int nf = 0; nf < 4; nf++)
                acc[mf][nf] = __builtin_amdgcn_mfma_f32_16x16x32_f16(a, b[nf], acc[mf][nf], 0, 0, 0);
        }
        if (km < 15) {
            int k0 = (km + 1) * 32;
#pragma unroll
            for (int p = 0; p < 2; p++) {
                int c = tid + p * 256, row = c & 127, kqs = c >> 7;
                short hs[8];
#pragma unroll
                for (int j = 0; j < 8; j++) {
                    float xf = __half2float(__ushort_as_half((unsigned short)xv[p][j]));
                    int k = k0 + kqs * 8 + j;
                    hs[j] = (short)__half_as_ushort(__float2half(fmaxf(fmaf(xf, sc[k], sh_[k]), 0.f)));
                }
                *(s16x8*)&A2[pb ^ 1][kqs * 1024 + row * 8] = *(s16x8*)hs;
            }
        }
        __syncthreads();
    }
#pragma unroll
    for (int nf = 0; nf < 4; nf++) {
        int col = nbase + wn * 64 + nf * 16 + r;
        float bb = b1[col];
#pragma unroll
        for (int mf = 0; mf < 8; mf++)
#pragma unroll
            for (int i = 0; i < 4; i++) {
                int row = rowbase + mf * 16 + kq * 4 + i;
                out[(size_t)row * 1024 + col] = acc[mf][nf][i] + bb;
            }
    }
}

extern "C" void kernel_launch(void* const* d_in, const int* in_sizes, int n_in,
                              void* d_out, int out_size, void* d_ws, size_t ws_size,
                              hipStream_t stream)
{
    const float* features = (const float*)d_in[0];
    const float* wg_w1 = (const float*)d_in[2];
    const float* wg_b1 = (const float*)d_in[3];
    const float* wg_w2 = (const float*)d_in[4];
    const float* fc_w  = (const float*)d_in[6];
    const float* fc_b  = (const float*)d_in[7];
    const float* mlp_w0 = (const float*)d_in[8];
    const float* mlp_b0 = (const float*)d_in[9];
    const float* bn_g  = (const float*)d_in[10];
    const float* bn_b  = (const float*)d_in[11];
    const float* mlp_w1 = (const float*)d_in[12];
    const float* mlp_b1 = (const float*)d_in[13];
    float* out = (float*)d_out;

    char* ws = (char*)d_ws;
    float* w_scores  = (float*)(ws + 0);          // 73856 f32
    float* stats     = (float*)(ws + 295424);     // 1024 f32
    float* scaleshift= (float*)(ws + 299520);     // 1024 f32
    int*   meta      = (int*)  (ws + 303616);     // 128*4
    int*   idx_sel   = (int*)  (ws + 305664);     // 22016 i32
    int*   cin_list  = (int*)  (ws + 393728);     // 128*172
    int*   unc_list  = (int*)  (ws + 481792);     // 128*256
    float* rscore    = (float*)(ws + 612864);     // 128*256
    short* w1t       = (short*)(ws + 743936);     // wg_w1^T f16 [512][512]
    short* w0t       = (short*)(ws + 1268224);    // mlp_w0^T f16 [512][512]
    short* mw1t      = (short*)(ws + 1792512);    // mlp_w1^T f16 [1024][512]
    short* fct       = (short*)(ws + 2841088);    // fc_w^T  f16 [1024][512]
    short* sel_h     = (short*)(ws + 3889664);    // sel f16 [22016][512]
    short* x1h       = (short*)(ws + 26434048);   // x1  f16 [22016][512]
    // total ws use ~ 46.7 MB

    zero_kernel<<<289, 256, 0, stream>>>(w_scores, stats);
    transpose_f16_kernel<<<dim3(16, 8, 4), 256, 0, stream>>>(
        wg_w1, mlp_w0, mlp_w1, fc_w, w1t, w0t, mw1t, fct);
    wg_f16_kernel<<<dim3(2, 577), 256, 0, stream>>>(
        features, w1t, wg_b1, wg_w2, w_scores);
    topk2_kernel<<<B_, 512, 0, stream>>>(w_scores, cin_list, unc_list, meta);
    refine_kernel<<<dim3(32, B_), 256, 0, stream>>>(
        features, wg_w1, wg_b1, wg_w2, unc_list, meta, rscore);
    select_kernel<<<B_, 256, 0, stream>>>(cin_list, unc_list, rscore, meta, idx_sel);
    gather_norm_kernel<<<M_SEL, 128, 0, stream>>>(features, idx_sel, sel_h);
    gemm_x1_kernel<<<dim3(2, 172), 256, 0, stream>>>(
        sel_h, w0t, mlp_b0, x1h, stats);
    bn_finalize_kernel<<<1, 512, 0, stream>>>(stats, bn_g, bn_b, scaleshift);
    gemm_out2_kernel<<<dim3(4, 172), 256, 0, stream>>>(
        sel_h, fct, fc_b, x1h, mw1t, scaleshift, mlp_b1, out);
}